// Round 12
// baseline (792.386 us; speedup 1.0000x reference)
//
#include <hip/hip_runtime.h>
#include <hip/hip_bf16.h>
#include <cstdint>

typedef __attribute__((ext_vector_type(8))) short short8x;   // 8 bf16 (4 VGPRs)
typedef __attribute__((ext_vector_type(4))) float f32x4;     // MFMA C/D

static constexpr int T    = 4096;
static constexpr int HD   = 1024;
static constexpr int FD   = 4096;
static constexpr int NE   = 8;
static constexpr int P    = T * 2;
static constexpr int PPAD = P + 128;
static constexpr int MAXT = P / 128 + NE;   // 72 (128-row tiles), % 8 == 0
static constexpr int RTB  = 16;
static constexpr int RNB  = T / RTB;

struct TileDesc { int e; int start; int rows; int pad; };

__device__ __forceinline__ uint16_t f2bf(float f) {
  uint32_t u = __builtin_bit_cast(uint32_t, f);
  u += 0x7FFFu + ((u >> 16) & 1u);
  return (uint16_t)(u >> 16);
}
__device__ __forceinline__ float bf2f(uint16_t b) {
  uint32_t u = ((uint32_t)b) << 16;
  return __builtin_bit_cast(float, u);
}

// ---------------- x fp32 -> bf16 ----------------
__global__ __launch_bounds__(256) void cvt_x_kernel(const float* __restrict__ x,
                                                    uint16_t* __restrict__ xb) {
  size_t i = ((size_t)blockIdx.x * 256 + threadIdx.x) * 4;
  float4 v = *(const float4*)&x[i];
  ushort4 o;
  o.x = f2bf(v.x); o.y = f2bf(v.y); o.z = f2bf(v.z); o.w = f2bf(v.w);
  *(ushort4*)&xb[i] = o;
}

// ------------- transpose + cvt: in [z][R][C] f32 -> out [z][C][R] bf16 -------------
__global__ __launch_bounds__(256) void transpose_cvt_kernel(
    const float* __restrict__ in, uint16_t* __restrict__ out, int R, int C) {
  __shared__ float tile[64][65];
  int z = blockIdx.z;
  const float* inp = in + (size_t)z * R * C;
  uint16_t* outp = out + (size_t)z * R * C;
  int r0 = blockIdx.y * 64, c0 = blockIdx.x * 64;
  int tid = threadIdx.x;
  int lr = tid >> 4;
  int lc4 = (tid & 15) * 4;
#pragma unroll
  for (int p = 0; p < 4; ++p) {
    float4 v = *(const float4*)&inp[(size_t)(r0 + lr + p * 16) * C + c0 + lc4];
    tile[lr + p * 16][lc4 + 0] = v.x;
    tile[lr + p * 16][lc4 + 1] = v.y;
    tile[lr + p * 16][lc4 + 2] = v.z;
    tile[lr + p * 16][lc4 + 3] = v.w;
  }
  __syncthreads();
#pragma unroll
  for (int p = 0; p < 4; ++p) {
    int c = lr + p * 16;
    ushort4 o;
    o.x = f2bf(tile[lc4 + 0][c]);
    o.y = f2bf(tile[lc4 + 1][c]);
    o.z = f2bf(tile[lc4 + 2][c]);
    o.w = f2bf(tile[lc4 + 3][c]);
    *(ushort4*)&outp[(size_t)(c0 + c) * R + r0 + lc4] = o;
  }
}

// ---------------- router ----------------
__global__ __launch_bounds__(256) void router_kernel(
    const float* __restrict__ x, const float* __restrict__ gate_w,
    int* __restrict__ topk_idx, float* __restrict__ topk_w,
    float* __restrict__ part_sums, int* __restrict__ part_counts) {
  __shared__ float g[NE * HD];
  __shared__ float ls[NE];
  __shared__ int   lc[NE];
  int tid = threadIdx.x;
  for (int i = tid; i < NE * HD; i += 256)
    g[(i & 7) * HD + (i >> 3)] = gate_w[i];
  if (tid < NE) { ls[tid] = 0.f; lc[tid] = 0; }
  __syncthreads();
  int wave = tid >> 6, lane = tid & 63;
  float psum[NE];
#pragma unroll
  for (int e = 0; e < NE; ++e) psum[e] = 0.f;

  for (int tt = 0; tt < RTB / 4; ++tt) {
    int t = blockIdx.x * RTB + wave * (RTB / 4) + tt;
    const float* xr = x + (size_t)t * HD;
    float acc[NE];
#pragma unroll
    for (int e = 0; e < NE; ++e) acc[e] = 0.f;
    for (int i = 0; i < HD / 64; ++i) {
      float xv = xr[lane + i * 64];
#pragma unroll
      for (int e = 0; e < NE; ++e) acc[e] += xv * g[e * HD + lane + i * 64];
    }
#pragma unroll
    for (int off = 32; off > 0; off >>= 1)
#pragma unroll
      for (int e = 0; e < NE; ++e) acc[e] += __shfl_down(acc[e], off);
    if (lane == 0) {
      float m = acc[0];
#pragma unroll
      for (int e = 1; e < NE; ++e) m = fmaxf(m, acc[e]);
      float p[NE], s = 0.f;
#pragma unroll
      for (int e = 0; e < NE; ++e) { p[e] = expf(acc[e] - m); s += p[e]; }
      float inv = 1.f / s;
#pragma unroll
      for (int e = 0; e < NE; ++e) { p[e] *= inv; psum[e] += p[e]; }
      int i0 = 0;
#pragma unroll
      for (int e = 1; e < NE; ++e) if (p[e] > p[i0]) i0 = e;
      int i1 = (i0 == 0) ? 1 : 0;
#pragma unroll
      for (int e = 0; e < NE; ++e) if (e != i0 && e != i1 && p[e] > p[i1]) i1 = e;
      float wsum = p[i0] + p[i1];
      topk_idx[t * 2] = i0; topk_idx[t * 2 + 1] = i1;
      topk_w[t * 2] = p[i0] / wsum; topk_w[t * 2 + 1] = p[i1] / wsum;
      atomicAdd(&lc[i0], 1); atomicAdd(&lc[i1], 1);
    }
  }
  if (lane == 0)
#pragma unroll
    for (int e = 0; e < NE; ++e) atomicAdd(&ls[e], psum[e]);
  __syncthreads();
  if (tid < NE) {
    part_sums[blockIdx.x * NE + tid]   = ls[tid];
    part_counts[blockIdx.x * NE + tid] = lc[tid];
  }
}

// ---------------- finalize ----------------
__global__ __launch_bounds__(64) void finalize_kernel(
    const int* __restrict__ part_counts, const float* __restrict__ part_sums,
    int* __restrict__ offsets, TileDesc* __restrict__ desc,
    int* __restrict__ ntiles, float* __restrict__ aux_out) {
  __shared__ int   csh[NE];
  __shared__ float ssh[NE];
  int tid = threadIdx.x;
  if (tid < NE) {
    int c = 0; float s = 0.f;
    for (int b = 0; b < RNB; ++b) {
      c += part_counts[b * NE + tid];
      s += part_sums[b * NE + tid];
    }
    csh[tid] = c; ssh[tid] = s;
  }
  __syncthreads();
  if (tid == 0) {
    int off = 0, nt = 0;
    for (int e = 0; e < NE; ++e) {
      offsets[e] = off;
      int c = csh[e];
      for (int i = 0; i < c; i += 128) {
        int rows = c - i; if (rows > 128) rows = 128;
        desc[nt].e = e; desc[nt].start = off + i; desc[nt].rows = rows; desc[nt].pad = 0;
        nt++;
      }
      off += c;
    }
    *ntiles = nt;
    float aux = 0.f;
    for (int e = 0; e < NE; ++e) {
      float mean = ssh[e] / (float)T;
      aux += mean * mean;
    }
    *aux_out = (float)NE * aux;
  }
}

// ---------------- scatter ----------------
__global__ __launch_bounds__(256) void scatter_kernel(
    const int* __restrict__ topk_idx, const int* __restrict__ offsets,
    int* __restrict__ fill, int* __restrict__ pair_tok, int* __restrict__ tok_pos) {
  int t = blockIdx.x * 256 + threadIdx.x;
  int lane = threadIdx.x & 63;
  unsigned long long below = (lane == 63) ? ~0ull >> 1
                                          : ((1ull << (lane + 1)) - 1) >> 1;
#pragma unroll
  for (int k = 0; k < 2; ++k) {
    int e = topk_idx[t * 2 + k];
    int pos = 0;
    for (int ex = 0; ex < NE; ++ex) {
      unsigned long long m = __ballot(e == ex);
      if (e == ex) {
        int leader = __ffsll((long long)m) - 1;
        int cnt = __popcll(m);
        int base = 0;
        if (lane == leader) base = atomicAdd(&fill[ex], cnt);
        base = __shfl(base, leader);
        pos = base + __popcll(m & below);
      }
    }
    int pp = offsets[e] + pos;
    pair_tok[pp] = t;
    tok_pos[t * 2 + k] = pp;
  }
}

// ---------------- MFMA GEMM: pure-register (no LDS, no barriers) ----------------
// C[rows,ND] = A[rows,KD] * Bw[e][ND,KD]^T (+bias, opt relu)
// Per wave per K-step (BK=32): 8 global dwordx4 loads (A 4, B 4; 16 rows x 64B
// lines each, L1/L2-resident via R8's XCD/supertile mapping) + 16 MFMA.
// Frags double-buffered in two NAMED register sets (static indexing, rule #20);
// waves fully independent -> TLP hides L2 latency, zero barrier drain.
// Per-lane mapping identical to the LDS copy R8 held -> correctness preserved.
template <int KD, int ND, int NBG, int EPI>
__global__ __launch_bounds__(256) void moe_gemm_reg(
    const uint16_t* __restrict__ Abase, const int* __restrict__ pair_tok,
    const uint16_t* __restrict__ Bw, const float* __restrict__ bias,
    uint16_t* __restrict__ Cout, const TileDesc* __restrict__ desc,
    const int* __restrict__ ntiles) {
  constexpr int SM = MAXT / 8;      // 9 mt-tiles per XCD
  constexpr int NT = KD / 32;

  int orig = blockIdx.x;
  int xcd = orig & 7, local = orig >> 3;
  int nbq = local / (SM * NBG);
  int rem = local % (SM * NBG);
  int mt  = xcd * SM + rem / NBG;
  int nb  = nbq * NBG + rem % NBG;
  if (mt >= *ntiles) return;
  TileDesc d = desc[mt];

  int tid = threadIdx.x, lane = tid & 63, wave = tid >> 6;
  int wm = wave >> 1, wn = wave & 1;
  int l15 = lane & 15, lk = lane >> 4;

  // per-lane operand row pointers (resolved once; gather folded in here)
  const uint16_t* ap[4];
  const uint16_t* bp[4];
#pragma unroll
  for (int i = 0; i < 4; ++i) {
    int r = wm * 64 + i * 16 + l15;
    int gr;
    if constexpr (EPI == 0) gr = (r < d.rows) ? pair_tok[d.start + r] : 0;
    else                    gr = d.start + r;
    ap[i] = Abase + (size_t)gr * KD + lk * 8;
  }
#pragma unroll
  for (int j = 0; j < 4; ++j)
    bp[j] = Bw + ((size_t)d.e * ND + (size_t)nb * 128 + wn * 64 + j * 16 + l15) * KD + lk * 8;

  f32x4 acc[4][4];
#pragma unroll
  for (int i = 0; i < 4; ++i)
#pragma unroll
    for (int j = 0; j < 4; ++j) acc[i][j] = (f32x4){0.f, 0.f, 0.f, 0.f};

  short8x aX[4], bX[4], aY[4], bY[4];

#define LOAD_SET(af, bf, kb)                                         \
  do {                                                               \
    _Pragma("unroll")                                                \
    for (int i = 0; i < 4; ++i)                                      \
      af[i] = *(const short8x*)(ap[i] + (kb));                       \
    _Pragma("unroll")                                                \
    for (int j = 0; j < 4; ++j)                                      \
      bf[j] = *(const short8x*)(bp[j] + (kb));                       \
  } while (0)

#define MFMA_SET(af, bf)                                             \
  do {                                                               \
    _Pragma("unroll")                                                \
    for (int i = 0; i < 4; ++i)                                      \
      _Pragma("unroll")                                              \
      for (int j = 0; j < 4; ++j)                                    \
        acc[i][j] = __builtin_amdgcn_mfma_f32_16x16x32_bf16(         \
            af[i], bf[j], acc[i][j], 0, 0, 0);                       \
  } while (0)

  LOAD_SET(aX, bX, 0);
  for (int kt = 0; kt < NT; kt += 2) {
    if (kt + 1 < NT) LOAD_SET(aY, bY, (kt + 1) * 32);
    MFMA_SET(aX, bX);
    if (kt + 2 < NT) LOAD_SET(aX, bX, (kt + 2) * 32);
    if (kt + 1 < NT) MFMA_SET(aY, bY);
  }
#undef LOAD_SET
#undef MFMA_SET

  // epilogue: C/D layout col=lane&15, row=(lane>>4)*4+q  [measured m89]
  int rq = lk * 4;
  int cl = l15;
#pragma unroll
  for (int i = 0; i < 4; ++i) {
    int rb = wm * 64 + i * 16 + rq;
#pragma unroll
    for (int j = 0; j < 4; ++j) {
      int col = nb * 128 + wn * 64 + j * 16 + cl;
      float bv = bias[d.e * ND + col];
#pragma unroll
      for (int q = 0; q < 4; ++q) {
        int r = rb + q;
        if (r < d.rows) {
          float v = acc[i][j][q] + bv;
          if (EPI == 0) v = fmaxf(v, 0.f);
          Cout[(size_t)(d.start + r) * ND + col] = f2bf(v);
        }
      }
    }
  }
}

// ---------------- combine ----------------
__global__ __launch_bounds__(256) void combine_kernel(
    const uint16_t* __restrict__ po, const int* __restrict__ tok_pos,
    const float* __restrict__ topk_w, float* __restrict__ out) {
  int t = blockIdx.x;
  int c = threadIdx.x * 4;
  int p0 = tok_pos[t * 2], p1 = tok_pos[t * 2 + 1];
  float w0 = topk_w[t * 2], w1 = topk_w[t * 2 + 1];
  ushort4 a = *(const ushort4*)&po[(size_t)p0 * HD + c];
  ushort4 b = *(const ushort4*)&po[(size_t)p1 * HD + c];
  float4 o;
  o.x = w0 * bf2f(a.x) + w1 * bf2f(b.x);
  o.y = w0 * bf2f(a.y) + w1 * bf2f(b.y);
  o.z = w0 * bf2f(a.z) + w1 * bf2f(b.z);
  o.w = w0 * bf2f(a.w) + w1 * bf2f(b.w);
  *(float4*)&out[(size_t)t * HD + c] = o;
}

extern "C" void kernel_launch(void* const* d_in, const int* in_sizes, int n_in,
                              void* d_out, int out_size, void* d_ws, size_t ws_size,
                              hipStream_t stream) {
  const float* x      = (const float*)d_in[0];
  const float* gate_w = (const float*)d_in[1];
  const float* w1     = (const float*)d_in[2];
  const float* b1     = (const float*)d_in[3];
  const float* w2     = (const float*)d_in[4];
  const float* b2     = (const float*)d_in[5];
  float* out = (float*)d_out;
  (void)in_sizes; (void)n_in; (void)out_size; (void)ws_size;

  char* w = (char*)d_ws;
  size_t off = 0;
  auto alloc = [&](size_t bytes) -> void* {
    void* p = w + off;
    off = (off + bytes + 255) & ~(size_t)255;
    return p;
  };
  int*      meta     = (int*)alloc(256);
  int*      fill     = meta;
  int*      offsets  = (int*)alloc(256);
  int*      ntiles   = offsets + 8;
  TileDesc* desc     = (TileDesc*)alloc(sizeof(TileDesc) * 128);
  int*      topk_idx = (int*)alloc(sizeof(int) * P);
  float*    topk_w   = (float*)alloc(sizeof(float) * P);
  int*      tok_pos  = (int*)alloc(sizeof(int) * P);
  int*      pair_tok = (int*)alloc(sizeof(int) * PPAD);
  float*    psums    = (float*)alloc(sizeof(float) * RNB * NE);
  int*      pcounts  = (int*)alloc(sizeof(int) * RNB * NE);
  uint16_t* xb       = (uint16_t*)alloc((size_t)T * HD * 2);
  uint16_t* w1t      = (uint16_t*)alloc((size_t)NE * FD * HD * 2);
  uint16_t* w2t      = (uint16_t*)alloc((size_t)NE * HD * FD * 2);
  uint16_t* hidden   = (uint16_t*)alloc((size_t)PPAD * FD * 2);
  uint16_t* pout     = (uint16_t*)alloc((size_t)PPAD * HD * 2);

  hipMemsetAsync(meta, 0, 256, stream);
  cvt_x_kernel<<<(T * HD) / 1024, 256, 0, stream>>>(x, xb);
  transpose_cvt_kernel<<<dim3(FD / 64, HD / 64, NE), 256, 0, stream>>>(w1, w1t, HD, FD);
  transpose_cvt_kernel<<<dim3(HD / 64, FD / 64, NE), 256, 0, stream>>>(w2, w2t, FD, HD);
  router_kernel<<<RNB, 256, 0, stream>>>(x, gate_w, topk_idx, topk_w, psums, pcounts);
  finalize_kernel<<<1, 64, 0, stream>>>(pcounts, psums, offsets, desc, ntiles,
                                        out + (size_t)T * HD);
  scatter_kernel<<<T / 256, 256, 0, stream>>>(topk_idx, offsets, fill, pair_tok, tok_pos);
  // fc1: gather+relu; grid = 32nb * 72mt = 2304
  moe_gemm_reg<HD, FD, 4, 0><<<(FD / 128) * MAXT, 256, 0, stream>>>(
      xb, pair_tok, w1t, b1, hidden, desc, ntiles);
  // fc2: contiguous; grid = 8nb * 72mt = 576
  moe_gemm_reg<FD, HD, 8, 1><<<(HD / 128) * MAXT, 256, 0, stream>>>(
      hidden, pair_tok, w2t, b2, pout, desc, ntiles);
  combine_kernel<<<T, 256, 0, stream>>>(pout, tok_pos, topk_w, out);
}

// Round 13
// 377.554 us; speedup vs baseline: 2.0987x; 2.0987x over previous
//
#include <hip/hip_runtime.h>
#include <hip/hip_bf16.h>
#include <cstdint>

#define AS1 __attribute__((address_space(1)))
#define AS3 __attribute__((address_space(3)))

typedef __attribute__((ext_vector_type(8))) short short8x;   // 8 bf16 (4 VGPRs)
typedef __attribute__((ext_vector_type(4))) float f32x4;     // MFMA C/D

static constexpr int T    = 4096;
static constexpr int HD   = 1024;
static constexpr int FD   = 4096;
static constexpr int NE   = 8;
static constexpr int P    = T * 2;
static constexpr int PPAD = P + 128;
static constexpr int MAXT = P / 128 + NE;   // 72 (128-row tiles), % 8 == 0
static constexpr int RTB  = 16;
static constexpr int RNB  = T / RTB;        // 256 router blocks

// fused-grid role sizes
static constexpr int TW1G = (FD / 64) * (HD / 64) * NE;  // 8192 transpose-w1 blocks
static constexpr int CVTG = (T * HD) / 1024;             // 4096 cvt_x blocks
static constexpr int FC1G = (FD / 128) * MAXT;           // 2304 fc1 gemm blocks
static constexpr int TW2G = (HD / 64) * (FD / 64) * NE;  // 8192 transpose-w2 blocks

struct TileDesc { int e; int start; int rows; int pad; };

__device__ __forceinline__ uint16_t f2bf(float f) {
  uint32_t u = __builtin_bit_cast(uint32_t, f);
  u += 0x7FFFu + ((u >> 16) & 1u);
  return (uint16_t)(u >> 16);
}
__device__ __forceinline__ float bf2f(uint16_t b) {
  uint32_t u = ((uint32_t)b) << 16;
  return __builtin_bit_cast(float, u);
}
__device__ __forceinline__ void gload_lds16(const void* g, void* l) {
  __builtin_amdgcn_global_load_lds((const AS1 uint32_t*)g, (AS3 uint32_t*)l, 16, 0, 0);
}

// ---------------- role: transpose + cvt (in [z][R][C] f32 -> out [z][C][R] bf16) ----------------
__device__ __forceinline__ void transpose_role(
    const float* __restrict__ in, uint16_t* __restrict__ out,
    int R, int C, int bi, float* tile /* 64x65 */) {
  int nbc = C / 64;
  int nbr = R / 64;
  int cx = bi % nbc;
  int ry = (bi / nbc) % nbr;
  int z  = bi / (nbc * nbr);
  const float* inp = in + (size_t)z * R * C;
  uint16_t* outp = out + (size_t)z * R * C;
  int r0 = ry * 64, c0 = cx * 64;
  int tid = threadIdx.x;
  int lr = tid >> 4;
  int lc4 = (tid & 15) * 4;
#pragma unroll
  for (int p = 0; p < 4; ++p) {
    float4 v = *(const float4*)&inp[(size_t)(r0 + lr + p * 16) * C + c0 + lc4];
    tile[(lr + p * 16) * 65 + lc4 + 0] = v.x;
    tile[(lr + p * 16) * 65 + lc4 + 1] = v.y;
    tile[(lr + p * 16) * 65 + lc4 + 2] = v.z;
    tile[(lr + p * 16) * 65 + lc4 + 3] = v.w;
  }
  __syncthreads();
#pragma unroll
  for (int p = 0; p < 4; ++p) {
    int c = lr + p * 16;
    ushort4 o;
    o.x = f2bf(tile[(lc4 + 0) * 65 + c]);
    o.y = f2bf(tile[(lc4 + 1) * 65 + c]);
    o.z = f2bf(tile[(lc4 + 2) * 65 + c]);
    o.w = f2bf(tile[(lc4 + 3) * 65 + c]);
    *(ushort4*)&outp[(size_t)(c0 + c) * R + r0 + lc4] = o;
  }
}

// ---------------- role: x fp32 -> bf16 ----------------
__device__ __forceinline__ void cvt_role(const float* __restrict__ x,
                                         uint16_t* __restrict__ xb, int bi) {
  size_t i = ((size_t)bi * 256 + threadIdx.x) * 4;
  float4 v = *(const float4*)&x[i];
  ushort4 o;
  o.x = f2bf(v.x); o.y = f2bf(v.y); o.z = f2bf(v.z); o.w = f2bf(v.w);
  *(ushort4*)&xb[i] = o;
}

// ---------------- role: router (per-block partial sums/counts, zero global atomics) ----------------
__device__ __forceinline__ void router_role(
    const float* __restrict__ x, const float* __restrict__ gate_w,
    int* __restrict__ topk_idx, float* __restrict__ topk_w,
    float* __restrict__ part_sums, int* __restrict__ part_counts,
    int rb, char* smem) {
  float* g  = (float*)smem;              // 32 KB: [e][h]
  float* ls = (float*)(smem + 32768);    // 8 floats
  int*   lc = (int*)(smem + 32768 + 32); // 8 ints
  int tid = threadIdx.x;
  for (int i = tid; i < NE * HD; i += 256)
    g[(i & 7) * HD + (i >> 3)] = gate_w[i];
  if (tid < NE) { ls[tid] = 0.f; lc[tid] = 0; }
  __syncthreads();
  int wave = tid >> 6, lane = tid & 63;
  float psum[NE];
#pragma unroll
  for (int e = 0; e < NE; ++e) psum[e] = 0.f;

  for (int tt = 0; tt < RTB / 4; ++tt) {
    int t = rb * RTB + wave * (RTB / 4) + tt;
    const float* xr = x + (size_t)t * HD;
    float acc[NE];
#pragma unroll
    for (int e = 0; e < NE; ++e) acc[e] = 0.f;
    for (int i = 0; i < HD / 64; ++i) {
      float xv = xr[lane + i * 64];
#pragma unroll
      for (int e = 0; e < NE; ++e) acc[e] += xv * g[e * HD + lane + i * 64];
    }
#pragma unroll
    for (int off = 32; off > 0; off >>= 1)
#pragma unroll
      for (int e = 0; e < NE; ++e) acc[e] += __shfl_down(acc[e], off);
    if (lane == 0) {
      float m = acc[0];
#pragma unroll
      for (int e = 1; e < NE; ++e) m = fmaxf(m, acc[e]);
      float p[NE], s = 0.f;
#pragma unroll
      for (int e = 0; e < NE; ++e) { p[e] = expf(acc[e] - m); s += p[e]; }
      float inv = 1.f / s;
#pragma unroll
      for (int e = 0; e < NE; ++e) { p[e] *= inv; psum[e] += p[e]; }
      int i0 = 0;
#pragma unroll
      for (int e = 1; e < NE; ++e) if (p[e] > p[i0]) i0 = e;
      int i1 = (i0 == 0) ? 1 : 0;
#pragma unroll
      for (int e = 0; e < NE; ++e) if (e != i0 && e != i1 && p[e] > p[i1]) i1 = e;
      float wsum = p[i0] + p[i1];
      topk_idx[t * 2] = i0; topk_idx[t * 2 + 1] = i1;
      topk_w[t * 2] = p[i0] / wsum; topk_w[t * 2 + 1] = p[i1] / wsum;
      atomicAdd(&lc[i0], 1); atomicAdd(&lc[i1], 1);
    }
  }
  if (lane == 0)
#pragma unroll
    for (int e = 0; e < NE; ++e) atomicAdd(&ls[e], psum[e]);
  __syncthreads();
  if (tid < NE) {
    part_sums[rb * NE + tid]   = ls[tid];
    part_counts[rb * NE + tid] = lc[tid];
  }
}

// ---------------- fused prep: transpose w1 | cvt x | router (independent roles) ----------------
__global__ __launch_bounds__(256) void prep_kernel(
    const float* __restrict__ x, const float* __restrict__ gate_w,
    const float* __restrict__ w1,
    uint16_t* __restrict__ xb, uint16_t* __restrict__ w1t,
    int* __restrict__ topk_idx, float* __restrict__ topk_w,
    float* __restrict__ part_sums, int* __restrict__ part_counts) {
  __shared__ __align__(16) char smem[33024];
  int b = blockIdx.x;
  if (b < TW1G) {
    transpose_role(w1, w1t, HD, FD, b, (float*)smem);
  } else if (b < TW1G + CVTG) {
    cvt_role(x, xb, b - TW1G);
  } else {
    router_role(x, gate_w, topk_idx, topk_w, part_sums, part_counts,
                b - TW1G - CVTG, smem);
  }
}

// ---------------- finalize ----------------
__global__ __launch_bounds__(64) void finalize_kernel(
    const int* __restrict__ part_counts, const float* __restrict__ part_sums,
    int* __restrict__ offsets, TileDesc* __restrict__ desc,
    int* __restrict__ ntiles, float* __restrict__ aux_out) {
  __shared__ int   csh[NE];
  __shared__ float ssh[NE];
  int tid = threadIdx.x;
  if (tid < NE) {
    int c = 0; float s = 0.f;
    for (int b = 0; b < RNB; ++b) {
      c += part_counts[b * NE + tid];
      s += part_sums[b * NE + tid];
    }
    csh[tid] = c; ssh[tid] = s;
  }
  __syncthreads();
  if (tid == 0) {
    int off = 0, nt = 0;
    for (int e = 0; e < NE; ++e) {
      offsets[e] = off;
      int c = csh[e];
      for (int i = 0; i < c; i += 128) {
        int rows = c - i; if (rows > 128) rows = 128;
        desc[nt].e = e; desc[nt].start = off + i; desc[nt].rows = rows; desc[nt].pad = 0;
        nt++;
      }
      off += c;
    }
    *ntiles = nt;
    float aux = 0.f;
    for (int e = 0; e < NE; ++e) {
      float mean = ssh[e] / (float)T;
      aux += mean * mean;
    }
    *aux_out = (float)NE * aux;
  }
}

// ---------------- scatter ----------------
__global__ __launch_bounds__(256) void scatter_kernel(
    const int* __restrict__ topk_idx, const int* __restrict__ offsets,
    int* __restrict__ fill, int* __restrict__ pair_tok, int* __restrict__ tok_pos) {
  int t = blockIdx.x * 256 + threadIdx.x;
  int lane = threadIdx.x & 63;
  unsigned long long below = (lane == 63) ? ~0ull >> 1
                                          : ((1ull << (lane + 1)) - 1) >> 1;
#pragma unroll
  for (int k = 0; k < 2; ++k) {
    int e = topk_idx[t * 2 + k];
    int pos = 0;
    for (int ex = 0; ex < NE; ++ex) {
      unsigned long long m = __ballot(e == ex);
      if (e == ex) {
        int leader = __ffsll((long long)m) - 1;
        int cnt = __popcll(m);
        int base = 0;
        if (lane == leader) base = atomicAdd(&fill[ex], cnt);
        base = __shfl(base, leader);
        pos = base + __popcll(m & below);
      }
    }
    int pp = offsets[e] + pos;
    pair_tok[pp] = t;
    tok_pos[t * 2 + k] = pp;
  }
}

// ---------------- role: MFMA GEMM (R8 structure, byte-identical logic) ----------------
// C[rows,ND] = A[rows,KD] * Bw[e][ND,KD]^T (+bias, opt relu)
// Mapping: XCD-bijective + per-XCD mt-supertile, nb grouped NBG (proven R8).
template <int KD, int ND, int NBG, int EPI>
__device__ __forceinline__ void gemm_role(
    char* smem, int orig,
    const uint16_t* __restrict__ Abase, const int* __restrict__ pair_tok,
    const uint16_t* __restrict__ Bw, const float* __restrict__ bias,
    uint16_t* __restrict__ Cout, const TileDesc* __restrict__ desc,
    const int* __restrict__ ntiles) {
  constexpr int SM = MAXT / 8;      // 9 mt-tiles per XCD

  int xcd = orig & 7, local = orig >> 3;
  int nbq = local / (SM * NBG);
  int rem = local % (SM * NBG);
  int mt  = xcd * SM + rem / NBG;
  int nb  = nbq * NBG + rem % NBG;
  if (mt >= *ntiles) return;
  TileDesc d = desc[mt];

  uint16_t* As = (uint16_t*)smem;            // 8192 B
  uint16_t* Bs = (uint16_t*)(smem + 8192);   // 8192 B
  int* rowA    = (int*)(smem + 16384);       // 512 B

  int tid = threadIdx.x, lane = tid & 63, wave = tid >> 6;
  int wm = wave >> 1, wn = wave & 1;

  int idx0 = (wave * 2 + 0) * 64 + lane;
  int idx1 = (wave * 2 + 1) * 64 + lane;
  int ar0 = idx0 >> 2, kc0 = idx0 & 3;
  int ar1 = idx1 >> 2, kc1 = idx1 & 3;

  int ra0, ra1;
  if constexpr (EPI == 0) {
    if (tid < 128) rowA[tid] = (tid < d.rows) ? pair_tok[d.start + tid] : 0;
    __syncthreads();
    ra0 = rowA[ar0]; ra1 = rowA[ar1];
  } else {
    ra0 = d.start + ar0; ra1 = d.start + ar1;
  }

  const uint16_t* Bbase = Bw + ((size_t)d.e * ND + (size_t)nb * 128) * KD;

  f32x4 acc[4][4];
#pragma unroll
  for (int i = 0; i < 4; ++i)
#pragma unroll
    for (int j = 0; j < 4; ++j) acc[i][j] = (f32x4){0.f, 0.f, 0.f, 0.f};

  for (int kt = 0; kt < KD / 32; ++kt) {
    if (kt) __syncthreads();
    int kb = kt * 32;
    gload_lds16(Abase + (size_t)ra0 * KD + kb + kc0 * 8, &As[(wave * 2 + 0) * 512]);
    gload_lds16(Abase + (size_t)ra1 * KD + kb + kc1 * 8, &As[(wave * 2 + 1) * 512]);
    gload_lds16(Bbase + (size_t)ar0 * KD + kb + kc0 * 8, &Bs[(wave * 2 + 0) * 512]);
    gload_lds16(Bbase + (size_t)ar1 * KD + kb + kc1 * 8, &Bs[(wave * 2 + 1) * 512]);
    __syncthreads();

    short8x af[4], bfr[4];
#pragma unroll
    for (int i = 0; i < 4; ++i)
      af[i] = *(const short8x*)&As[(wm * 64 + i * 16 + (lane & 15)) * 32 + (lane >> 4) * 8];
#pragma unroll
    for (int j = 0; j < 4; ++j)
      bfr[j] = *(const short8x*)&Bs[(wn * 64 + j * 16 + (lane & 15)) * 32 + (lane >> 4) * 8];
#pragma unroll
    for (int i = 0; i < 4; ++i)
#pragma unroll
      for (int j = 0; j < 4; ++j)
        acc[i][j] = __builtin_amdgcn_mfma_f32_16x16x32_bf16(af[i], bfr[j], acc[i][j], 0, 0, 0);
  }

  // epilogue: C/D layout col=lane&15, row=(lane>>4)*4+q  [measured m89]
  int rq = (lane >> 4) * 4;
  int cl = lane & 15;
#pragma unroll
  for (int i = 0; i < 4; ++i) {
    int rb = wm * 64 + i * 16 + rq;
#pragma unroll
    for (int j = 0; j < 4; ++j) {
      int col = nb * 128 + wn * 64 + j * 16 + cl;
      float bv = bias[d.e * ND + col];
#pragma unroll
      for (int q = 0; q < 4; ++q) {
        int r = rb + q;
        if (r < d.rows) {
          float v = acc[i][j][q] + bv;
          if (EPI == 0) v = fmaxf(v, 0.f);
          Cout[(size_t)(d.start + r) * ND + col] = f2bf(v);
        }
      }
    }
  }
}

// ---------------- fc1 fused with transpose-w2 (independent; fills idle CU slots) ----------------
__global__ __launch_bounds__(256) void fc1_fused_kernel(
    const uint16_t* __restrict__ xb, const int* __restrict__ pair_tok,
    const uint16_t* __restrict__ w1t, const float* __restrict__ b1,
    uint16_t* __restrict__ hidden, const TileDesc* __restrict__ desc,
    const int* __restrict__ ntiles,
    const float* __restrict__ w2, uint16_t* __restrict__ w2t) {
  __shared__ __align__(16) char smem[17408];
  int b = blockIdx.x;
  if (b < FC1G) {
    gemm_role<HD, FD, 4, 0>(smem, b, xb, pair_tok, w1t, b1, hidden, desc, ntiles);
  } else {
    transpose_role(w2, w2t, FD, HD, b - FC1G, (float*)smem);
  }
}

// ---------------- fc2 ----------------
__global__ __launch_bounds__(256) void fc2_kernel(
    const uint16_t* __restrict__ hidden, const uint16_t* __restrict__ w2t,
    const float* __restrict__ b2, uint16_t* __restrict__ pout,
    const TileDesc* __restrict__ desc, const int* __restrict__ ntiles) {
  __shared__ __align__(16) char smem[17408];
  gemm_role<FD, HD, 8, 1>(smem, blockIdx.x, hidden, nullptr, w2t, b2, pout, desc, ntiles);
}

// ---------------- combine ----------------
__global__ __launch_bounds__(256) void combine_kernel(
    const uint16_t* __restrict__ po, const int* __restrict__ tok_pos,
    const float* __restrict__ topk_w, float* __restrict__ out) {
  int t = blockIdx.x;
  int c = threadIdx.x * 4;
  int p0 = tok_pos[t * 2], p1 = tok_pos[t * 2 + 1];
  float w0 = topk_w[t * 2], w1 = topk_w[t * 2 + 1];
  ushort4 a = *(const ushort4*)&po[(size_t)p0 * HD + c];
  ushort4 b = *(const ushort4*)&po[(size_t)p1 * HD + c];
  float4 o;
  o.x = w0 * bf2f(a.x) + w1 * bf2f(b.x);
  o.y = w0 * bf2f(a.y) + w1 * bf2f(b.y);
  o.z = w0 * bf2f(a.z) + w1 * bf2f(b.z);
  o.w = w0 * bf2f(a.w) + w1 * bf2f(b.w);
  *(float4*)&out[(size_t)t * HD + c] = o;
}

extern "C" void kernel_launch(void* const* d_in, const int* in_sizes, int n_in,
                              void* d_out, int out_size, void* d_ws, size_t ws_size,
                              hipStream_t stream) {
  const float* x      = (const float*)d_in[0];
  const float* gate_w = (const float*)d_in[1];
  const float* w1     = (const float*)d_in[2];
  const float* b1     = (const float*)d_in[3];
  const float* w2     = (const float*)d_in[4];
  const float* b2     = (const float*)d_in[5];
  float* out = (float*)d_out;
  (void)in_sizes; (void)n_in; (void)out_size; (void)ws_size;

  char* w = (char*)d_ws;
  size_t off = 0;
  auto alloc = [&](size_t bytes) -> void* {
    void* p = w + off;
    off = (off + bytes + 255) & ~(size_t)255;
    return p;
  };
  int*      meta     = (int*)alloc(256);
  int*      fill     = meta;
  int*      offsets  = (int*)alloc(256);
  int*      ntiles   = offsets + 8;
  TileDesc* desc     = (TileDesc*)alloc(sizeof(TileDesc) * 128);
  int*      topk_idx = (int*)alloc(sizeof(int) * P);
  float*    topk_w   = (float*)alloc(sizeof(float) * P);
  int*      tok_pos  = (int*)alloc(sizeof(int) * P);
  int*      pair_tok = (int*)alloc(sizeof(int) * PPAD);
  float*    psums    = (float*)alloc(sizeof(float) * RNB * NE);
  int*      pcounts  = (int*)alloc(sizeof(int) * RNB * NE);
  uint16_t* xb       = (uint16_t*)alloc((size_t)T * HD * 2);
  uint16_t* w1t      = (uint16_t*)alloc((size_t)NE * FD * HD * 2);
  uint16_t* w2t      = (uint16_t*)alloc((size_t)NE * HD * FD * 2);
  uint16_t* hidden   = (uint16_t*)alloc((size_t)PPAD * FD * 2);
  uint16_t* pout     = (uint16_t*)alloc((size_t)PPAD * HD * 2);

  hipMemsetAsync(meta, 0, 256, stream);
  // prep: transpose-w1 (8192) | cvt_x (4096) | router (256) — independent roles
  prep_kernel<<<TW1G + CVTG + RNB, 256, 0, stream>>>(
      x, gate_w, w1, xb, w1t, topk_idx, topk_w, psums, pcounts);
  finalize_kernel<<<1, 64, 0, stream>>>(pcounts, psums, offsets, desc, ntiles,
                                        out + (size_t)T * HD);
  scatter_kernel<<<T / 256, 256, 0, stream>>>(topk_idx, offsets, fill, pair_tok, tok_pos);
  // fc1 (2304, issued first) | transpose-w2 (8192, fills idle slots behind fc1)
  fc1_fused_kernel<<<FC1G + TW2G, 256, 0, stream>>>(
      xb, pair_tok, w1t, b1, hidden, desc, ntiles, w2, w2t);
  // fc2: grid 8nb * 72mt = 576
  fc2_kernel<<<(HD / 128) * MAXT, 256, 0, stream>>>(
      hidden, w2t, b2, pout, desc, ntiles);
  combine_kernel<<<T, 256, 0, stream>>>(pout, tok_pos, topk_w, out);
}